// Round 5
// baseline (103.512 us; speedup 1.0000x reference)
//
#include <hip/hip_runtime.h>
#include <math.h>

#define T_UTT 50
#define H_DIM 512
#define B_DIM 4096
#define NWAVES 8
#define NT_PW 7      // ceil(T_UTT / NWAVES); waves 0-1 get 7 t's, waves 2-7 get 6
#define RED_PAD 66   // float2 row stride: 66*8=528 B -> 16B-aligned rows, staggered banks

typedef float f32x4 __attribute__((ext_vector_type(4)));

__device__ __forceinline__ float dot8(f32x4 a0, f32x4 a1, f32x4 b0, f32x4 b1) {
    float s = 0.f;
#pragma unroll
    for (int j = 0; j < 4; ++j) s += a0[j] * b0[j];
#pragma unroll
    for (int j = 0; j < 4; ++j) s += a1[j] * b1[j];
    return s;
}

// ds_swizzle butterfly add step (BitMode: xor_mask<<10 | 0x1F), zero index VALU
#define SWZ_ADD(x, imm) \
    (x) += __int_as_float(__builtin_amdgcn_ds_swizzle(__float_as_int(x), (imm)))

// 512 threads = 8 waves per block, one block per batch row b.
// __launch_bounds__(512, 4): caps VGPR at 128 -> 2 blocks/CU (16 waves).
__global__ __launch_bounds__(512, 4) void wseq_attn(const float* __restrict__ Q,
                                                    const float* __restrict__ U,
                                                    float* __restrict__ Out) {
    const int b    = blockIdx.x;
    const int tid  = threadIdx.x;
    const int lane = tid & 63;
    const int wave = tid >> 6;
    const int h0   = lane << 3;   // 8 floats per lane, 64 lanes = 512 = H_DIM

    __shared__ float2 s_red[T_UTT][RED_PAD];  // per-lane (dot, norm2) partials
    __shared__ float  s_score[T_UTT];
    __shared__ float  s_w[T_UTT + 1];
    __shared__ float  s_q[H_DIM];
    __shared__ float  s_part[NWAVES][H_DIM];

    // ---- query fragment (f32x4-typed pointer: +1 == +16 bytes) ----
    const f32x4* qp = reinterpret_cast<const f32x4*>(Q + (size_t)b * H_DIM + h0);
    f32x4 q0 = qp[0];
    f32x4 q1 = qp[1];

    // ---- Phase A: issue ALL utterance loads (plain loads; NT regressed in R4) ----
    f32x4 u0[NT_PW], u1[NT_PW];
#pragma unroll
    for (int i = 0; i < NT_PW; ++i) {
        const int t = wave + NWAVES * i;
        if (t < T_UTT) {
            const f32x4* up =
                reinterpret_cast<const f32x4*>(U + ((size_t)t * B_DIM + b) * H_DIM + h0);
            u0[i] = up[0];
            u1[i] = up[1];
        }
    }

    // stash q for the fully-parallel epilogue
    if (wave == 0) {
        *reinterpret_cast<f32x4*>(&s_q[h0])     = q0;
        *reinterpret_cast<f32x4*>(&s_q[h0 + 4]) = q1;
    }

    // ---- q norm^2: one butterfly per wave (all lanes get result) ----
    float qn = dot8(q0, q1, q0, q1);
#pragma unroll
    for (int m = 32; m; m >>= 1) qn += __shfl_xor(qn, m, 64);
    const float q_inv = rsqrtf(qn);

    // ---- Phase B: per-lane partials, pure FMA, one float2 LDS write per t ----
#pragma unroll
    for (int i = 0; i < NT_PW; ++i) {
        const int t = wave + NWAVES * i;
        if (t < T_UTT) {
            float d = dot8(q0, q1, u0[i], u1[i]);
            float n = dot8(u0[i], u1[i], u0[i], u1[i]);
            s_red[t][lane] = make_float2(d, n);
        }
    }
    __syncthreads();

    // ---- Phase B': 8 threads per t reduce its 64 partials ----
    if (tid < 8 * T_UTT) {
        const int t = tid >> 3;
        const int j = tid & 7;
        const f32x4* rp = reinterpret_cast<const f32x4*>(&s_red[t][j * 8]);
        f32x4 v0 = rp[0], v1 = rp[1], v2 = rp[2], v3 = rp[3];
        float d = ((v0[0] + v0[2]) + (v1[0] + v1[2])) +
                  ((v2[0] + v2[2]) + (v3[0] + v3[2]));
        float n = ((v0[1] + v0[3]) + (v1[1] + v1[3])) +
                  ((v2[1] + v2[3]) + (v3[1] + v3[3]));
        // 3-step butterfly across the 8 group threads (consecutive lanes, masks 1/2/4)
        SWZ_ADD(d, 0x041F); SWZ_ADD(n, 0x041F);
        SWZ_ADD(d, 0x081F); SWZ_ADD(n, 0x081F);
        SWZ_ADD(d, 0x101F); SWZ_ADD(n, 0x101F);
        if (j == 0) s_score[t] = d * q_inv * rsqrtf(n);
    }
    __syncthreads();

    // ---- softmax over 51 scores: wave 0 only, wave-parallel ----
    if (wave == 0) {
        float v = (lane < T_UTT) ? s_score[lane]
                                 : ((lane == T_UTT) ? 1.0f : -INFINITY);
        float mx = v;
#pragma unroll
        for (int m = 32; m; m >>= 1) mx = fmaxf(mx, __shfl_xor(mx, m, 64));
        float e = __expf(v - mx);
        float sum = e;
#pragma unroll
        for (int m = 32; m; m >>= 1) sum += __shfl_xor(sum, m, 64);
        if (lane <= T_UTT) s_w[lane] = e / sum;
    }
    __syncthreads();

    // ---- Phase D: weighted sum from registers; weights via LDS broadcast ----
    float acc[8] = {0.f, 0.f, 0.f, 0.f, 0.f, 0.f, 0.f, 0.f};
#pragma unroll
    for (int i = 0; i < NT_PW; ++i) {
        const int t = wave + NWAVES * i;
        if (t < T_UTT) {
            const float w = s_w[t];   // wave-uniform address -> free broadcast
            acc[0] += w * u0[i][0]; acc[1] += w * u0[i][1];
            acc[2] += w * u0[i][2]; acc[3] += w * u0[i][3];
            acc[4] += w * u1[i][0]; acc[5] += w * u1[i][1];
            acc[6] += w * u1[i][2]; acc[7] += w * u1[i][3];
        }
    }
    f32x4* sp = reinterpret_cast<f32x4*>(&s_part[wave][h0]);
    sp[0] = (f32x4){acc[0], acc[1], acc[2], acc[3]};
    sp[1] = (f32x4){acc[4], acc[5], acc[6], acc[7]};
    __syncthreads();

    // ---- epilogue: fully parallel — each of 512 threads owns one h ----
    float o = s_w[T_UTT] * s_q[tid];
#pragma unroll
    for (int w = 0; w < NWAVES; ++w) o += s_part[w][tid];
    Out[(size_t)b * H_DIM + tid] = o;
}

extern "C" void kernel_launch(void* const* d_in, const int* in_sizes, int n_in,
                              void* d_out, int out_size, void* d_ws, size_t ws_size,
                              hipStream_t stream) {
    const float* Q = (const float*)d_in[0];   // [B, H]
    const float* U = (const float*)d_in[1];   // [T, B, H]
    float* Out = (float*)d_out;               // [B, H]
    wseq_attn<<<dim3(B_DIM), dim3(512), 0, stream>>>(Q, U, Out);
}

// Round 6
// 90.298 us; speedup vs baseline: 1.1463x; 1.1463x over previous
//
#include <hip/hip_runtime.h>
#include <math.h>

#define T_UTT 50
#define H_DIM 512
#define B_DIM 4096
#define NWAVES 16
#define NT_PW 4     // ceil(50/16): waves 0-1 get 4 t's, waves 2-15 get 3

typedef float f32x4 __attribute__((ext_vector_type(4)));

__device__ __forceinline__ float dot8(f32x4 a0, f32x4 a1, f32x4 b0, f32x4 b1) {
    float s = 0.f;
#pragma unroll
    for (int j = 0; j < 4; ++j) s += a0[j] * b0[j];
#pragma unroll
    for (int j = 0; j < 4; ++j) s += a1[j] * b1[j];
    return s;
}

// 1024 threads = 16 waves per block, one block per batch row b.
// __launch_bounds__(1024, 8): 8 waves/EU -> 32 waves/CU (2 blocks) -> caps
// VGPR at 64. Per-thread u-slice is 32 VGPRs (4 t x 2 float4); peak live ~58.
__global__ __launch_bounds__(1024, 8) void wseq_attn(const float* __restrict__ Q,
                                                     const float* __restrict__ U,
                                                     float* __restrict__ Out) {
    const int b    = blockIdx.x;
    const int tid  = threadIdx.x;
    const int lane = tid & 63;
    const int wave = tid >> 6;
    const int h0   = lane << 3;   // 8 floats per lane, 64 lanes = 512 = H_DIM

    __shared__ float s_score[T_UTT];      // un-normalized: dot * rsqrt(n)
    __shared__ float s_w[T_UTT + 1];      // softmax weights (s_w[50] = query's)
    __shared__ float s_q[H_DIM];
    __shared__ float s_part[NWAVES][H_DIM];

    // ---- query fragment (f32x4-typed pointer: +1 == +16 bytes) ----
    const f32x4* qp = reinterpret_cast<const f32x4*>(Q + (size_t)b * H_DIM + h0);
    f32x4 q0 = qp[0];
    f32x4 q1 = qp[1];

    // ---- Phase A: issue this wave's utterance loads (plain; NT regressed) ----
    f32x4 u0[NT_PW], u1[NT_PW];
#pragma unroll
    for (int i = 0; i < NT_PW; ++i) {
        const int t = wave + NWAVES * i;
        if (t < T_UTT) {
            const f32x4* up =
                reinterpret_cast<const f32x4*>(U + ((size_t)t * B_DIM + b) * H_DIM + h0);
            u0[i] = up[0];
            u1[i] = up[1];
        }
    }

    // stash q for the epilogue
    if (wave == 0) {
        *reinterpret_cast<f32x4*>(&s_q[h0])     = q0;
        *reinterpret_cast<f32x4*>(&s_q[h0 + 4]) = q1;
    }

    // ---- q norm^2: wave 0 only (q_inv folded into softmax input) ----
    float q_inv = 0.f;
    if (wave == 0) {
        float qn = dot8(q0, q1, q0, q1);
#pragma unroll
        for (int m = 32; m; m >>= 1) qn += __shfl_xor(qn, m, 64);
        q_inv = rsqrtf(qn);
    }

    // ---- Phase B: dot + norm^2 butterflies; lane 0 writes d*rsqrt(n) ----
#pragma unroll
    for (int i = 0; i < NT_PW; ++i) {
        const int t = wave + NWAVES * i;
        if (t < T_UTT) {
            float d = dot8(q0, q1, u0[i], u1[i]);
            float n = dot8(u0[i], u1[i], u0[i], u1[i]);
#pragma unroll
            for (int m = 32; m; m >>= 1) {
                d += __shfl_xor(d, m, 64);
                n += __shfl_xor(n, m, 64);
            }
            if (lane == 0) s_score[t] = d * rsqrtf(n);
        }
    }
    __syncthreads();

    // ---- softmax over 51 scores: wave 0, lane t owns score t ----
    if (wave == 0) {
        float v = (lane < T_UTT) ? s_score[lane] * q_inv
                                 : ((lane == T_UTT) ? 1.0f : -INFINITY);
        float mx = v;
#pragma unroll
        for (int m = 32; m; m >>= 1) mx = fmaxf(mx, __shfl_xor(mx, m, 64));
        float e = __expf(v - mx);
        float sum = e;
#pragma unroll
        for (int m = 32; m; m >>= 1) sum += __shfl_xor(sum, m, 64);
        if (lane <= T_UTT) s_w[lane] = e / sum;
    }
    __syncthreads();

    // ---- Phase D: weighted sum from registers; weights via LDS broadcast ----
    float acc[8] = {0.f, 0.f, 0.f, 0.f, 0.f, 0.f, 0.f, 0.f};
#pragma unroll
    for (int i = 0; i < NT_PW; ++i) {
        const int t = wave + NWAVES * i;
        if (t < T_UTT) {
            const float w = s_w[t];   // wave-uniform address -> broadcast
            acc[0] += w * u0[i][0]; acc[1] += w * u0[i][1];
            acc[2] += w * u0[i][2]; acc[3] += w * u0[i][3];
            acc[4] += w * u1[i][0]; acc[5] += w * u1[i][1];
            acc[6] += w * u1[i][2]; acc[7] += w * u1[i][3];
        }
    }
    f32x4* sp = reinterpret_cast<f32x4*>(&s_part[wave][h0]);
    sp[0] = (f32x4){acc[0], acc[1], acc[2], acc[3]};
    sp[1] = (f32x4){acc[4], acc[5], acc[6], acc[7]};
    __syncthreads();

    // ---- epilogue: threads 0..511 each own one h ----
    if (tid < H_DIM) {
        float o = s_w[T_UTT] * s_q[tid];
#pragma unroll
        for (int w = 0; w < NWAVES; ++w) o += s_part[w][tid];
        Out[(size_t)b * H_DIM + tid] = o;
    }
}

extern "C" void kernel_launch(void* const* d_in, const int* in_sizes, int n_in,
                              void* d_out, int out_size, void* d_ws, size_t ws_size,
                              hipStream_t stream) {
    const float* Q = (const float*)d_in[0];   // [B, H]
    const float* U = (const float*)d_in[1];   // [T, B, H]
    float* Out = (float*)d_out;               // [B, H]
    wseq_attn<<<dim3(B_DIM), dim3(1024), 0, stream>>>(Q, U, Out);
}